// Round 3
// baseline (1184.776 us; speedup 1.0000x reference)
//
#include <hip/hip_runtime.h>
#include <hip/hip_bf16.h>

// GIN forward, MI355X. Sizes fixed by the reference.
constexpr int N_NODES  = 100000;
constexpr int N_EDGES  = 1280000;
constexpr int HDIM     = 64;
constexpr int N_GRAPHS = 128;
constexpr int N_RES    = 4;
constexpr int CAP      = 64;   // max in-degree slots (Poisson(12.8): P(deg>64) ~ e-60)

// ---------------- CSR build: XCD-binned single pass ----------------
// grid = 8 ranges x 128 chunks. block b: dst range (b&7) [matches XCD under
// round-robin], edge chunk (b>>3). Each edge processed by exactly one block;
// all writes to a node row come from (mostly) one XCD -> L2 line coalescing.
constexpr int RNG = 8;
constexpr int RSZ = N_NODES / RNG;      // 12500
constexpr int CHUNKS = 128;
constexpr int CSZ = N_EDGES / CHUNKS;   // 10000

__global__ void fill_kernel(const int* __restrict__ ei,
                            int* __restrict__ cnt, int* __restrict__ csr) {
  int b = blockIdx.x;
  int lo = (b & (RNG - 1)) * RSZ;
  int hi = lo + RSZ;
  int base = (b >> 3) * CSZ;
  for (int i = base + threadIdx.x * 4; i < base + CSZ; i += 256 * 4) {
    int4 d4 = *(const int4*)&ei[N_EDGES + i];
    int4 s4 = *(const int4*)&ei[i];
    if (d4.x >= lo && d4.x < hi) { int p = atomicAdd(&cnt[d4.x], 1); csr[d4.x * CAP + (p & (CAP - 1))] = s4.x; }
    if (d4.y >= lo && d4.y < hi) { int p = atomicAdd(&cnt[d4.y], 1); csr[d4.y * CAP + (p & (CAP - 1))] = s4.y; }
    if (d4.z >= lo && d4.z < hi) { int p = atomicAdd(&cnt[d4.z], 1); csr[d4.z * CAP + (p & (CAP - 1))] = s4.z; }
    if (d4.w >= lo && d4.w < hi) { int p = atomicAdd(&cnt[d4.w], 1); csr[d4.w * CAP + (p & (CAP - 1))] = s4.w; }
  }
}

// goff[g] = lower_bound(batch, g) over sorted batch ids
__global__ void goff_kernel(const int* __restrict__ batch, int* __restrict__ goff) {
  int g = threadIdx.x;
  if (g > N_GRAPHS) return;
  int lo = 0, hi = N_NODES;
  while (lo < hi) {
    int mid = (lo + hi) >> 1;
    if (batch[mid] < g) lo = mid + 1; else hi = mid;
  }
  goff[g] = lo;
}

// ---------------- fused GIN conv: 8 nodes per wave ----------------
// lane = feature j. Weights transposed in LDS (pad 68: b128 read is 8-phase
// optimal). One weight read feeds 8 fma (8-node reuse). Gather: 16 CSR slots
// scalar-loaded upfront, 16 independent gathers with safe self-index for
// empty slots, corrected by -(16-deg)*hj; deg>16 tail loops (rare).
template <bool RESID>
__global__ __launch_bounds__(256, 3)
void conv_kernel(const float* __restrict__ hin, float* __restrict__ hout,
                 const int* __restrict__ cnt, const int* __restrict__ csr,
                 const float* __restrict__ W1, const float* __restrict__ b1,
                 const float* __restrict__ W2, const float* __restrict__ b2,
                 const float* __restrict__ gam, const float* __restrict__ bet,
                 const float* __restrict__ rm, const float* __restrict__ rv) {
  __shared__ __align__(16) float w1t[64 * 68];
  __shared__ __align__(16) float w2t[64 * 68];
  __shared__ __align__(16) float zbuf[4][8][64];
  __shared__ __align__(16) float z2buf[4][8][64];

  int t = threadIdx.x;
  for (int i = t; i < 4096; i += 256) {
    int k = i >> 6, j = i & 63;
    w1t[j * 68 + k] = W1[i];
    w2t[j * 68 + k] = W2[i];
  }
  __syncthreads();

  int j = t & 63;
  int wid = t >> 6;
  float b1r = b1[j], b2r = b2[j];
  float sc = gam[j] * rsqrtf(rv[j] + 1e-5f);
  float sh = bet[j] - rm[j] * sc;

  constexpr int NTASK = N_NODES / 8;   // 12500, exact
  for (int w0 = blockIdx.x * 4 + wid; w0 < NTASK; w0 += gridDim.x * 4) {
    int nb = __builtin_amdgcn_readfirstlane(w0) * 8;
    float hj[8];

    // ---- gather phase ----
    for (int m = 0; m < 8; ++m) {
      int n = nb + m;
      const int* row = csr + (size_t)n * CAP;
      int4 r0 = *(const int4*)(row + 0);
      int4 r1 = *(const int4*)(row + 4);
      int4 r2 = *(const int4*)(row + 8);
      int4 r3 = *(const int4*)(row + 12);
      int deg = cnt[n];
      deg = deg > CAP ? CAP : deg;
      float h0 = hin[(size_t)n * 64 + j];
      hj[m] = h0;
      int i0  = (0  < deg) ? r0.x : n;
      int i1  = (1  < deg) ? r0.y : n;
      int i2  = (2  < deg) ? r0.z : n;
      int i3  = (3  < deg) ? r0.w : n;
      int i4  = (4  < deg) ? r1.x : n;
      int i5  = (5  < deg) ? r1.y : n;
      int i6  = (6  < deg) ? r1.z : n;
      int i7  = (7  < deg) ? r1.w : n;
      int i8  = (8  < deg) ? r2.x : n;
      int i9  = (9  < deg) ? r2.y : n;
      int i10 = (10 < deg) ? r2.z : n;
      int i11 = (11 < deg) ? r2.w : n;
      int i12 = (12 < deg) ? r3.x : n;
      int i13 = (13 < deg) ? r3.y : n;
      int i14 = (14 < deg) ? r3.z : n;
      int i15 = (15 < deg) ? r3.w : n;
      float v0  = hin[(size_t)i0  * 64 + j];
      float v1  = hin[(size_t)i1  * 64 + j];
      float v2  = hin[(size_t)i2  * 64 + j];
      float v3  = hin[(size_t)i3  * 64 + j];
      float v4  = hin[(size_t)i4  * 64 + j];
      float v5  = hin[(size_t)i5  * 64 + j];
      float v6  = hin[(size_t)i6  * 64 + j];
      float v7  = hin[(size_t)i7  * 64 + j];
      float v8  = hin[(size_t)i8  * 64 + j];
      float v9  = hin[(size_t)i9  * 64 + j];
      float v10 = hin[(size_t)i10 * 64 + j];
      float v11 = hin[(size_t)i11 * 64 + j];
      float v12 = hin[(size_t)i12 * 64 + j];
      float v13 = hin[(size_t)i13 * 64 + j];
      float v14 = hin[(size_t)i14 * 64 + j];
      float v15 = hin[(size_t)i15 * 64 + j];
      float z = ((v0 + v1) + (v2 + v3)) + ((v4 + v5) + (v6 + v7))
              + ((v8 + v9) + (v10 + v11)) + ((v12 + v13) + (v14 + v15));
      int degc = deg < 16 ? deg : 16;
      z += h0 - (float)(16 - degc) * h0;      // self + remove dummy slots
      for (int q = 16; q < deg; ++q) z += hin[(size_t)row[q] * 64 + j];
      zbuf[wid][m][j] = z;
    }

    // ---- matvec 1: a1 = relu(z @ W1 + b1) ----
    float acc[8];
#pragma unroll
    for (int m = 0; m < 8; ++m) acc[m] = b1r;
#pragma unroll
    for (int k = 0; k < 64; k += 4) {
      float4 ww = *(const float4*)&w1t[j * 68 + k];
#pragma unroll
      for (int m = 0; m < 8; ++m) {
        float4 zz = *(const float4*)&zbuf[wid][m][k];   // same-addr broadcast
        acc[m] = fmaf(zz.x, ww.x, acc[m]);
        acc[m] = fmaf(zz.y, ww.y, acc[m]);
        acc[m] = fmaf(zz.z, ww.z, acc[m]);
        acc[m] = fmaf(zz.w, ww.w, acc[m]);
      }
    }
#pragma unroll
    for (int m = 0; m < 8; ++m) z2buf[wid][m][j] = fmaxf(acc[m], 0.0f);

    // ---- matvec 2: a2 = relu(a1 @ W2 + b2) ----
#pragma unroll
    for (int m = 0; m < 8; ++m) acc[m] = b2r;
#pragma unroll
    for (int k = 0; k < 64; k += 4) {
      float4 ww = *(const float4*)&w2t[j * 68 + k];
#pragma unroll
      for (int m = 0; m < 8; ++m) {
        float4 zz = *(const float4*)&z2buf[wid][m][k];
        acc[m] = fmaf(zz.x, ww.x, acc[m]);
        acc[m] = fmaf(zz.y, ww.y, acc[m]);
        acc[m] = fmaf(zz.z, ww.z, acc[m]);
        acc[m] = fmaf(zz.w, ww.w, acc[m]);
      }
    }

    // ---- BN (+residual) + store ----
#pragma unroll
    for (int m = 0; m < 8; ++m) {
      float y = fmaxf(acc[m], 0.0f) * sc + sh;
      if (RESID) y += hj[m];
      hout[(size_t)(nb + m) * 64 + j] = y;
    }
  }
}

// ---------------- head: tanh(h @ W + b), 8 nodes per wave ----------------
__global__ __launch_bounds__(256, 4)
void head_kernel(const float* __restrict__ hin, float* __restrict__ hb,
                 const float* __restrict__ W, const float* __restrict__ b) {
  __shared__ __align__(16) float wt[64 * 68];
  __shared__ __align__(16) float zbuf[4][8][64];
  int t = threadIdx.x;
  for (int i = t; i < 4096; i += 256) {
    int k = i >> 6, j = i & 63;
    wt[j * 68 + k] = W[i];
  }
  __syncthreads();

  int j = t & 63;
  int wid = t >> 6;
  float br = b[j];
  constexpr int NTASK = N_NODES / 8;
  for (int w0 = blockIdx.x * 4 + wid; w0 < NTASK; w0 += gridDim.x * 4) {
    int nb = __builtin_amdgcn_readfirstlane(w0) * 8;
#pragma unroll
    for (int m = 0; m < 8; ++m) zbuf[wid][m][j] = hin[(size_t)(nb + m) * 64 + j];
    float acc[8];
#pragma unroll
    for (int m = 0; m < 8; ++m) acc[m] = br;
#pragma unroll
    for (int k = 0; k < 64; k += 4) {
      float4 ww = *(const float4*)&wt[j * 68 + k];
#pragma unroll
      for (int m = 0; m < 8; ++m) {
        float4 zz = *(const float4*)&zbuf[wid][m][k];
        acc[m] = fmaf(zz.x, ww.x, acc[m]);
        acc[m] = fmaf(zz.y, ww.y, acc[m]);
        acc[m] = fmaf(zz.z, ww.z, acc[m]);
        acc[m] = fmaf(zz.w, ww.w, acc[m]);
      }
    }
#pragma unroll
    for (int m = 0; m < 8; ++m) hb[(size_t)(nb + m) * 64 + j] = tanhf(acc[m]);
  }
}

// ---------------- per-graph mean pool (batch is sorted) ----------------
__global__ void pool_kernel(const float* __restrict__ hb, const int* __restrict__ goff,
                            float* __restrict__ out) {
  __shared__ float red[4][64];
  int g = blockIdx.x;
  int s = goff[g], e = goff[g + 1];
  int j = threadIdx.x & 63, w = threadIdx.x >> 6;
  float acc = 0.0f;
  for (int r = s + w; r < e; r += 4) acc += hb[(size_t)r * 64 + j];
  red[w][j] = acc;
  __syncthreads();
  if (w == 0) {
    float tt = red[0][j] + red[1][j] + red[2][j] + red[3][j];
    out[g * 64 + j] = tt / fmaxf((float)(e - s), 1.0f);
  }
}

// ---------------- launch ----------------
extern "C" void kernel_launch(void* const* d_in, const int* in_sizes, int n_in,
                              void* d_out, int out_size, void* d_ws, size_t ws_size,
                              hipStream_t stream) {
  const float* x     = (const float*)d_in[0];
  const int*   ei    = (const int*)d_in[1];
  const int*   batch = (const int*)d_in[2];
  const float* c1_W1 = (const float*)d_in[3];
  const float* c1_b1 = (const float*)d_in[4];
  const float* c1_W2 = (const float*)d_in[5];
  const float* c1_b2 = (const float*)d_in[6];
  const float* c1_g  = (const float*)d_in[7];
  const float* c1_be = (const float*)d_in[8];
  const float* c1_m  = (const float*)d_in[9];
  const float* c1_v  = (const float*)d_in[10];
  const float* cs_W1 = (const float*)d_in[11];
  const float* cs_b1 = (const float*)d_in[12];
  const float* cs_W2 = (const float*)d_in[13];
  const float* cs_b2 = (const float*)d_in[14];
  const float* cs_g  = (const float*)d_in[15];
  const float* cs_be = (const float*)d_in[16];
  const float* cs_m  = (const float*)d_in[17];
  const float* cs_v  = (const float*)d_in[18];
  const float* lin_W = (const float*)d_in[19];
  const float* lin_b = (const float*)d_in[20];
  float* out = (float*)d_out;

  size_t cur = 0;
  auto take = [&](size_t bytes) -> void* {
    void* p = (char*)d_ws + cur;
    cur += (bytes + 255) & ~(size_t)255;
    return p;
  };
  int* cnt  = (int*)take(N_NODES * sizeof(int));
  size_t zbytes = cur;                       // only cnt needs zeroing
  int* goff = (int*)take((N_GRAPHS + 1) * sizeof(int));
  int* csr  = (int*)take((size_t)N_NODES * CAP * sizeof(int));
  float* bufA = (float*)take((size_t)N_NODES * HDIM * sizeof(float));
  float* bufB = (float*)take((size_t)N_NODES * HDIM * sizeof(float));
  (void)ws_size; (void)in_sizes; (void)n_in; (void)out_size;

  hipMemsetAsync(d_ws, 0, zbytes, stream);

  fill_kernel<<<RNG * CHUNKS, 256, 0, stream>>>(ei, cnt, csr);
  goff_kernel<<<1, 256, 0, stream>>>(batch, goff);

  // conv1: x -> bufA
  conv_kernel<false><<<1563, 256, 0, stream>>>(x, bufA, cnt, csr,
      c1_W1, c1_b1, c1_W2, c1_b2, c1_g, c1_be, c1_m, c1_v);

  // 4 residual convs, ping-pong A<->B
  float* srcp = bufA;
  float* dstp = bufB;
  for (int l = 0; l < N_RES; ++l) {
    conv_kernel<true><<<1563, 256, 0, stream>>>(srcp, dstp, cnt, csr,
        cs_W1 + l * 4096, cs_b1 + l * 64, cs_W2 + l * 4096, cs_b2 + l * 64,
        cs_g + l * 64, cs_be + l * 64, cs_m + l * 64, cs_v + l * 64);
    float* tmp = srcp; srcp = dstp; dstp = tmp;
  }
  // final h is in srcp (== bufA); head writes dstp (== bufB)
  head_kernel<<<1563, 256, 0, stream>>>(srcp, dstp, lin_W, lin_b);
  pool_kernel<<<N_GRAPHS, 256, 0, stream>>>(dstp, goff, out);
}

// Round 4
// 744.495 us; speedup vs baseline: 1.5914x; 1.5914x over previous
//
#include <hip/hip_runtime.h>
#include <hip/hip_bf16.h>

// GIN forward, MI355X. Sizes fixed by the reference.
constexpr int N_NODES  = 100000;
constexpr int N_EDGES  = 1280000;
constexpr int HDIM     = 64;
constexpr int N_GRAPHS = 128;
constexpr int N_RES    = 4;
constexpr int CAP      = 64;   // max in-degree slots (Poisson(12.8): P(deg>64) ~ e-60)

// wave-uniform lane broadcast via v_readlane (scalar port; stays OFF the LDS pipe)
__device__ __forceinline__ float lanebc(float v, int l) {
  return __int_as_float(__builtin_amdgcn_readlane(__float_as_int(v), l));
}

// ---------------- CSR build: XCD-binned single pass ----------------
constexpr int RNG = 8;
constexpr int RSZ = N_NODES / RNG;      // 12500
constexpr int CHUNKS = 128;
constexpr int CSZ = N_EDGES / CHUNKS;   // 10000

__global__ void fill_kernel(const int* __restrict__ ei,
                            int* __restrict__ cnt, int* __restrict__ csr) {
  int b = blockIdx.x;
  int lo = (b & (RNG - 1)) * RSZ;
  int hi = lo + RSZ;
  int base = (b >> 3) * CSZ;
  for (int i = base + threadIdx.x * 4; i < base + CSZ; i += 256 * 4) {
    int4 d4 = *(const int4*)&ei[N_EDGES + i];
    int4 s4 = *(const int4*)&ei[i];
    if (d4.x >= lo && d4.x < hi) { int p = atomicAdd(&cnt[d4.x], 1); csr[d4.x * CAP + (p & (CAP - 1))] = s4.x; }
    if (d4.y >= lo && d4.y < hi) { int p = atomicAdd(&cnt[d4.y], 1); csr[d4.y * CAP + (p & (CAP - 1))] = s4.y; }
    if (d4.z >= lo && d4.z < hi) { int p = atomicAdd(&cnt[d4.z], 1); csr[d4.z * CAP + (p & (CAP - 1))] = s4.z; }
    if (d4.w >= lo && d4.w < hi) { int p = atomicAdd(&cnt[d4.w], 1); csr[d4.w * CAP + (p & (CAP - 1))] = s4.w; }
  }
}

// goff[g] = lower_bound(batch, g) over sorted batch ids
__global__ void goff_kernel(const int* __restrict__ batch, int* __restrict__ goff) {
  int g = threadIdx.x;
  if (g > N_GRAPHS) return;
  int lo = 0, hi = N_NODES;
  while (lo < hi) {
    int mid = (lo + hi) >> 1;
    if (batch[mid] < g) lo = mid + 1; else hi = mid;
  }
  goff[g] = lo;
}

// ---------------- fused GIN conv: zero-LDS, W in registers ----------------
// lane j holds column j of W1 and W2 (128 VGPR). z stays in a register
// (lane j = feature j); the k-broadcast uses v_readlane -> fma scalar port.
// 8 nodes per wave amortize the CSR slot loads; all loops fully unrolled
// (static indexing -> registers, rule #20).
template <bool RESID>
__global__ __launch_bounds__(256, 2)
void conv_kernel(const float* __restrict__ hin, float* __restrict__ hout,
                 const int* __restrict__ cnt, const int* __restrict__ csr,
                 const float* __restrict__ W1, const float* __restrict__ b1,
                 const float* __restrict__ W2, const float* __restrict__ b2,
                 const float* __restrict__ gam, const float* __restrict__ bet,
                 const float* __restrict__ rm, const float* __restrict__ rv) {
  int t = threadIdx.x;
  int j = t & 63;
  int wid = t >> 6;

  float w1r[64], w2r[64];
#pragma unroll
  for (int k = 0; k < 64; ++k) {
    w1r[k] = W1[k * 64 + j];
    w2r[k] = W2[k * 64 + j];
  }
  float b1r = b1[j], b2r = b2[j];
  float sc = gam[j] * rsqrtf(rv[j] + 1e-5f);
  float sh = bet[j] - rm[j] * sc;

  constexpr int NTASK = N_NODES / 8;   // 12500, exact
  for (int w0 = blockIdx.x * 4 + wid; w0 < NTASK; w0 += gridDim.x * 4) {
    int nb = __builtin_amdgcn_readfirstlane(w0) * 8;
    float z[8], hj[8];

    // ---- gather phase (one node at a time; 16 parallel row reads) ----
    for (int m = 0; m < 8; ++m) {
      int n = nb + m;
      const int* row = csr + (size_t)n * CAP;
      int4 r0 = *(const int4*)(row + 0);
      int4 r1 = *(const int4*)(row + 4);
      int4 r2 = *(const int4*)(row + 8);
      int4 r3 = *(const int4*)(row + 12);
      int deg = cnt[n];
      deg = deg > CAP ? CAP : deg;
      float h0 = hin[(size_t)n * 64 + j];
      int i0  = (0  < deg) ? r0.x : n;
      int i1  = (1  < deg) ? r0.y : n;
      int i2  = (2  < deg) ? r0.z : n;
      int i3  = (3  < deg) ? r0.w : n;
      int i4  = (4  < deg) ? r1.x : n;
      int i5  = (5  < deg) ? r1.y : n;
      int i6  = (6  < deg) ? r1.z : n;
      int i7  = (7  < deg) ? r1.w : n;
      int i8  = (8  < deg) ? r2.x : n;
      int i9  = (9  < deg) ? r2.y : n;
      int i10 = (10 < deg) ? r2.z : n;
      int i11 = (11 < deg) ? r2.w : n;
      int i12 = (12 < deg) ? r3.x : n;
      int i13 = (13 < deg) ? r3.y : n;
      int i14 = (14 < deg) ? r3.z : n;
      int i15 = (15 < deg) ? r3.w : n;
      float v0  = hin[(size_t)i0  * 64 + j];
      float v1  = hin[(size_t)i1  * 64 + j];
      float v2  = hin[(size_t)i2  * 64 + j];
      float v3  = hin[(size_t)i3  * 64 + j];
      float v4  = hin[(size_t)i4  * 64 + j];
      float v5  = hin[(size_t)i5  * 64 + j];
      float v6  = hin[(size_t)i6  * 64 + j];
      float v7  = hin[(size_t)i7  * 64 + j];
      float v8  = hin[(size_t)i8  * 64 + j];
      float v9  = hin[(size_t)i9  * 64 + j];
      float v10 = hin[(size_t)i10 * 64 + j];
      float v11 = hin[(size_t)i11 * 64 + j];
      float v12 = hin[(size_t)i12 * 64 + j];
      float v13 = hin[(size_t)i13 * 64 + j];
      float v14 = hin[(size_t)i14 * 64 + j];
      float v15 = hin[(size_t)i15 * 64 + j];
      float zz = ((v0 + v1) + (v2 + v3)) + ((v4 + v5) + (v6 + v7))
               + ((v8 + v9) + (v10 + v11)) + ((v12 + v13) + (v14 + v15));
      int degc = deg < 16 ? deg : 16;
      zz += h0 - (float)(16 - degc) * h0;     // self + remove dummy slots
      for (int q = 16; q < deg; ++q) zz += hin[(size_t)row[q] * 64 + j];
      z[m] = zz;
      hj[m] = h0;
    }

    // ---- matvec 1: a1 = relu(z @ W1 + b1); readlane broadcast ----
    float a1[8];
#pragma unroll
    for (int m = 0; m < 8; ++m) {
      float c0 = 0.f, c1 = 0.f, c2 = 0.f, c3 = 0.f;
#pragma unroll
      for (int k = 0; k < 64; k += 4) {
        c0 = fmaf(lanebc(z[m], k + 0), w1r[k + 0], c0);
        c1 = fmaf(lanebc(z[m], k + 1), w1r[k + 1], c1);
        c2 = fmaf(lanebc(z[m], k + 2), w1r[k + 2], c2);
        c3 = fmaf(lanebc(z[m], k + 3), w1r[k + 3], c3);
      }
      a1[m] = fmaxf(b1r + ((c0 + c1) + (c2 + c3)), 0.0f);
    }

    // ---- matvec 2 + ReLU + BN (+residual) + store ----
#pragma unroll
    for (int m = 0; m < 8; ++m) {
      float c0 = 0.f, c1 = 0.f, c2 = 0.f, c3 = 0.f;
#pragma unroll
      for (int k = 0; k < 64; k += 4) {
        c0 = fmaf(lanebc(a1[m], k + 0), w2r[k + 0], c0);
        c1 = fmaf(lanebc(a1[m], k + 1), w2r[k + 1], c1);
        c2 = fmaf(lanebc(a1[m], k + 2), w2r[k + 2], c2);
        c3 = fmaf(lanebc(a1[m], k + 3), w2r[k + 3], c3);
      }
      float a2 = fmaxf(b2r + ((c0 + c1) + (c2 + c3)), 0.0f);
      float y = a2 * sc + sh;
      if (RESID) y += hj[m];
      hout[(size_t)(nb + m) * 64 + j] = y;
    }
  }
}

// ---------------- head: tanh(h @ W + b), zero-LDS ----------------
__global__ __launch_bounds__(256, 3)
void head_kernel(const float* __restrict__ hin, float* __restrict__ hb,
                 const float* __restrict__ W, const float* __restrict__ b) {
  int t = threadIdx.x;
  int j = t & 63;
  int wid = t >> 6;
  float wr[64];
#pragma unroll
  for (int k = 0; k < 64; ++k) wr[k] = W[k * 64 + j];
  float br = b[j];

  constexpr int NTASK = N_NODES / 4;   // 25000, 4 nodes/wave
  for (int w0 = blockIdx.x * 4 + wid; w0 < NTASK; w0 += gridDim.x * 4) {
    int nb = __builtin_amdgcn_readfirstlane(w0) * 4;
    float h[4];
#pragma unroll
    for (int m = 0; m < 4; ++m) h[m] = hin[(size_t)(nb + m) * 64 + j];
#pragma unroll
    for (int m = 0; m < 4; ++m) {
      float c0 = 0.f, c1 = 0.f, c2 = 0.f, c3 = 0.f;
#pragma unroll
      for (int k = 0; k < 64; k += 4) {
        c0 = fmaf(lanebc(h[m], k + 0), wr[k + 0], c0);
        c1 = fmaf(lanebc(h[m], k + 1), wr[k + 1], c1);
        c2 = fmaf(lanebc(h[m], k + 2), wr[k + 2], c2);
        c3 = fmaf(lanebc(h[m], k + 3), wr[k + 3], c3);
      }
      hb[(size_t)(nb + m) * 64 + j] = tanhf(br + ((c0 + c1) + (c2 + c3)));
    }
  }
}

// ---------------- per-graph mean pool (batch is sorted) ----------------
__global__ void pool_kernel(const float* __restrict__ hb, const int* __restrict__ goff,
                            float* __restrict__ out) {
  __shared__ float red[4][64];
  int g = blockIdx.x;
  int s = goff[g], e = goff[g + 1];
  int j = threadIdx.x & 63, w = threadIdx.x >> 6;
  float acc = 0.0f;
  for (int r = s + w; r < e; r += 4) acc += hb[(size_t)r * 64 + j];
  red[w][j] = acc;
  __syncthreads();
  if (w == 0) {
    float tt = red[0][j] + red[1][j] + red[2][j] + red[3][j];
    out[g * 64 + j] = tt / fmaxf((float)(e - s), 1.0f);
  }
}

// ---------------- launch ----------------
extern "C" void kernel_launch(void* const* d_in, const int* in_sizes, int n_in,
                              void* d_out, int out_size, void* d_ws, size_t ws_size,
                              hipStream_t stream) {
  const float* x     = (const float*)d_in[0];
  const int*   ei    = (const int*)d_in[1];
  const int*   batch = (const int*)d_in[2];
  const float* c1_W1 = (const float*)d_in[3];
  const float* c1_b1 = (const float*)d_in[4];
  const float* c1_W2 = (const float*)d_in[5];
  const float* c1_b2 = (const float*)d_in[6];
  const float* c1_g  = (const float*)d_in[7];
  const float* c1_be = (const float*)d_in[8];
  const float* c1_m  = (const float*)d_in[9];
  const float* c1_v  = (const float*)d_in[10];
  const float* cs_W1 = (const float*)d_in[11];
  const float* cs_b1 = (const float*)d_in[12];
  const float* cs_W2 = (const float*)d_in[13];
  const float* cs_b2 = (const float*)d_in[14];
  const float* cs_g  = (const float*)d_in[15];
  const float* cs_be = (const float*)d_in[16];
  const float* cs_m  = (const float*)d_in[17];
  const float* cs_v  = (const float*)d_in[18];
  const float* lin_W = (const float*)d_in[19];
  const float* lin_b = (const float*)d_in[20];
  float* out = (float*)d_out;

  size_t cur = 0;
  auto take = [&](size_t bytes) -> void* {
    void* p = (char*)d_ws + cur;
    cur += (bytes + 255) & ~(size_t)255;
    return p;
  };
  int* cnt  = (int*)take(N_NODES * sizeof(int));
  size_t zbytes = cur;                       // only cnt needs zeroing
  int* goff = (int*)take((N_GRAPHS + 1) * sizeof(int));
  int* csr  = (int*)take((size_t)N_NODES * CAP * sizeof(int));
  float* bufA = (float*)take((size_t)N_NODES * HDIM * sizeof(float));
  float* bufB = (float*)take((size_t)N_NODES * HDIM * sizeof(float));
  (void)ws_size; (void)in_sizes; (void)n_in; (void)out_size;

  hipMemsetAsync(d_ws, 0, zbytes, stream);

  fill_kernel<<<RNG * CHUNKS, 256, 0, stream>>>(ei, cnt, csr);
  goff_kernel<<<1, 256, 0, stream>>>(batch, goff);

  // conv1: x -> bufA
  conv_kernel<false><<<1024, 256, 0, stream>>>(x, bufA, cnt, csr,
      c1_W1, c1_b1, c1_W2, c1_b2, c1_g, c1_be, c1_m, c1_v);

  // 4 residual convs, ping-pong A<->B
  float* srcp = bufA;
  float* dstp = bufB;
  for (int l = 0; l < N_RES; ++l) {
    conv_kernel<true><<<1024, 256, 0, stream>>>(srcp, dstp, cnt, csr,
        cs_W1 + l * 4096, cs_b1 + l * 64, cs_W2 + l * 4096, cs_b2 + l * 64,
        cs_g + l * 64, cs_be + l * 64, cs_m + l * 64, cs_v + l * 64);
    float* tmp = srcp; srcp = dstp; dstp = tmp;
  }
  // final h is in srcp (== bufA); head writes dstp (== bufB)
  head_kernel<<<1024, 256, 0, stream>>>(srcp, dstp, lin_W, lin_b);
  pool_kernel<<<N_GRAPHS, 256, 0, stream>>>(dstp, goff, out);
}

// Round 5
// 738.019 us; speedup vs baseline: 1.6053x; 1.0088x over previous
//
#include <hip/hip_runtime.h>
#include <hip/hip_bf16.h>

// GIN forward, MI355X. Sizes fixed by the reference.
constexpr int N_NODES  = 100000;
constexpr int N_EDGES  = 1280000;
constexpr int HDIM     = 64;
constexpr int N_GRAPHS = 128;
constexpr int N_RES    = 4;
constexpr int CAP      = 64;   // max in-degree slots (Poisson(12.8): P(deg>64) ~ e-60)

// ---------------- CSR build: XCD-binned single pass ----------------
constexpr int RNG = 8;
constexpr int RSZ = N_NODES / RNG;      // 12500
constexpr int CHUNKS = 128;
constexpr int CSZ = N_EDGES / CHUNKS;   // 10000

__global__ void fill_kernel(const int* __restrict__ ei,
                            int* __restrict__ cnt, int* __restrict__ csr) {
  int b = blockIdx.x;
  int lo = (b & (RNG - 1)) * RSZ;
  int hi = lo + RSZ;
  int base = (b >> 3) * CSZ;
  for (int i = base + threadIdx.x * 4; i < base + CSZ; i += 256 * 4) {
    int4 d4 = *(const int4*)&ei[N_EDGES + i];
    int4 s4 = *(const int4*)&ei[i];
    if (d4.x >= lo && d4.x < hi) { int p = atomicAdd(&cnt[d4.x], 1); csr[d4.x * CAP + (p & (CAP - 1))] = s4.x; }
    if (d4.y >= lo && d4.y < hi) { int p = atomicAdd(&cnt[d4.y], 1); csr[d4.y * CAP + (p & (CAP - 1))] = s4.y; }
    if (d4.z >= lo && d4.z < hi) { int p = atomicAdd(&cnt[d4.z], 1); csr[d4.z * CAP + (p & (CAP - 1))] = s4.z; }
    if (d4.w >= lo && d4.w < hi) { int p = atomicAdd(&cnt[d4.w], 1); csr[d4.w * CAP + (p & (CAP - 1))] = s4.w; }
  }
}

// goff[g] = lower_bound(batch, g) over sorted batch ids
__global__ void goff_kernel(const int* __restrict__ batch, int* __restrict__ goff) {
  int g = threadIdx.x;
  if (g > N_GRAPHS) return;
  int lo = 0, hi = N_NODES;
  while (lo < hi) {
    int mid = (lo + hi) >> 1;
    if (batch[mid] < g) lo = mid + 1; else hi = mid;
  }
  goff[g] = lo;
}

// ---------------- fused GIN conv: block = 64 nodes, 4 waves ----------------
// Gather: wave w gathers nodes [16w,16w+16) lane=feature (coalesced rows),
// z -> zbuf[node][feat] (pad 65: all LDS accesses 2-way = free).
// Matvec: lane=node; wave w computes out-features [16w,16w+16) for ALL 64
// nodes. Per k: 1 ds_read_b32 (z) + wave-uniform s_load of 16 W floats
// (SGPR operand -> fma scalar port, no broadcast instructions) + 16 fma.
template <bool RESID>
__global__ void conv_kernel(const float* __restrict__ hin, float* __restrict__ hout,
                            const int* __restrict__ cnt, const int* __restrict__ csr,
                            const float* __restrict__ W1, const float* __restrict__ b1,
                            const float* __restrict__ W2, const float* __restrict__ b2,
                            const float* __restrict__ gam, const float* __restrict__ bet,
                            const float* __restrict__ rm, const float* __restrict__ rv) {
  __shared__ float zbuf[64][65];

  const int t   = threadIdx.x;
  const int ln  = t & 63;
  const int wid = __builtin_amdgcn_readfirstlane(t >> 6);
  const int nb  = blockIdx.x * 64;
  const int valid = (nb + 64 <= N_NODES) ? 64 : (N_NODES - nb);

  // ---- gather phase: wave wid -> local nodes [16*wid, 16*wid+16) ----
  const int mlo = wid * 16;
  for (int m = mlo; m < mlo + 16; ++m) {
    if (m >= valid) break;
    const int n = nb + m;                       // block-uniform
    const int* row = csr + (size_t)n * CAP;
    int4 r0 = *(const int4*)(row + 0);
    int4 r1 = *(const int4*)(row + 4);
    int4 r2 = *(const int4*)(row + 8);
    int4 r3 = *(const int4*)(row + 12);
    int deg = cnt[n];
    deg = deg > CAP ? CAP : deg;
    float h0 = hin[(size_t)n * 64 + ln];
    int i0  = (0  < deg) ? r0.x : n;
    int i1  = (1  < deg) ? r0.y : n;
    int i2  = (2  < deg) ? r0.z : n;
    int i3  = (3  < deg) ? r0.w : n;
    int i4  = (4  < deg) ? r1.x : n;
    int i5  = (5  < deg) ? r1.y : n;
    int i6  = (6  < deg) ? r1.z : n;
    int i7  = (7  < deg) ? r1.w : n;
    int i8  = (8  < deg) ? r2.x : n;
    int i9  = (9  < deg) ? r2.y : n;
    int i10 = (10 < deg) ? r2.z : n;
    int i11 = (11 < deg) ? r2.w : n;
    int i12 = (12 < deg) ? r3.x : n;
    int i13 = (13 < deg) ? r3.y : n;
    int i14 = (14 < deg) ? r3.z : n;
    int i15 = (15 < deg) ? r3.w : n;
    float v0  = hin[(size_t)i0  * 64 + ln];
    float v1  = hin[(size_t)i1  * 64 + ln];
    float v2  = hin[(size_t)i2  * 64 + ln];
    float v3  = hin[(size_t)i3  * 64 + ln];
    float v4  = hin[(size_t)i4  * 64 + ln];
    float v5  = hin[(size_t)i5  * 64 + ln];
    float v6  = hin[(size_t)i6  * 64 + ln];
    float v7  = hin[(size_t)i7  * 64 + ln];
    float v8  = hin[(size_t)i8  * 64 + ln];
    float v9  = hin[(size_t)i9  * 64 + ln];
    float v10 = hin[(size_t)i10 * 64 + ln];
    float v11 = hin[(size_t)i11 * 64 + ln];
    float v12 = hin[(size_t)i12 * 64 + ln];
    float v13 = hin[(size_t)i13 * 64 + ln];
    float v14 = hin[(size_t)i14 * 64 + ln];
    float v15 = hin[(size_t)i15 * 64 + ln];
    float z = ((v0 + v1) + (v2 + v3)) + ((v4 + v5) + (v6 + v7))
            + ((v8 + v9) + (v10 + v11)) + ((v12 + v13) + (v14 + v15));
    int degc = deg < 16 ? deg : 16;
    z += h0 - (float)(16 - degc) * h0;          // self + remove dummy slots
    for (int q = 16; q < deg; ++q) z += hin[(size_t)row[q] * 64 + ln];
    zbuf[m][ln] = z;
  }
  __syncthreads();

  // ---- matvec 1: acc[f] = relu(z @ W1 + b1), f = jb..jb+15, node = ln ----
  const int jb = wid * 16;
  float acc[16];
#pragma unroll
  for (int f = 0; f < 16; ++f) acc[f] = b1[jb + f];
#pragma unroll
  for (int k = 0; k < 64; ++k) {
    float zk = zbuf[ln][k];
#pragma unroll
    for (int f = 0; f < 16; ++f)
      acc[f] = fmaf(zk, W1[k * 64 + jb + f], acc[f]);   // W chunk: s_load
  }
  __syncthreads();                                      // all zbuf reads done
#pragma unroll
  for (int f = 0; f < 16; ++f) zbuf[ln][jb + f] = fmaxf(acc[f], 0.0f);
  __syncthreads();                                      // a1 fully written

  // ---- matvec 2: acc[f] = a1 @ W2 + b2 ----
#pragma unroll
  for (int f = 0; f < 16; ++f) acc[f] = b2[jb + f];
#pragma unroll
  for (int k = 0; k < 64; ++k) {
    float zk = zbuf[ln][k];
#pragma unroll
    for (int f = 0; f < 16; ++f)
      acc[f] = fmaf(zk, W2[k * 64 + jb + f], acc[f]);
  }

  // ---- ReLU + BN (+residual) + store: lane owns one 64B line ----
  if (ln < valid) {
    const size_t base = (size_t)(nb + ln) * 64 + jb;
    float y[16];
#pragma unroll
    for (int f = 0; f < 16; ++f) {
      float sc = gam[jb + f] * rsqrtf(rv[jb + f] + 1e-5f);
      float sh = bet[jb + f] - rm[jb + f] * sc;
      y[f] = fmaxf(acc[f], 0.0f) * sc + sh;
    }
    if (RESID) {
#pragma unroll
      for (int c = 0; c < 4; ++c) {
        float4 r = *(const float4*)&hin[base + c * 4];
        y[c * 4 + 0] += r.x; y[c * 4 + 1] += r.y;
        y[c * 4 + 2] += r.z; y[c * 4 + 3] += r.w;
      }
    }
#pragma unroll
    for (int c = 0; c < 4; ++c) {
      float4 s = make_float4(y[c * 4 + 0], y[c * 4 + 1], y[c * 4 + 2], y[c * 4 + 3]);
      *(float4*)&hout[base + c * 4] = s;
    }
  }
}

// ---------------- head: tanh(h @ W + b), same structure ----------------
__global__ void head_kernel(const float* __restrict__ hin, float* __restrict__ hb,
                            const float* __restrict__ W, const float* __restrict__ b) {
  __shared__ float zbuf[64][65];
  const int t   = threadIdx.x;
  const int ln  = t & 63;
  const int wid = __builtin_amdgcn_readfirstlane(t >> 6);
  const int nb  = blockIdx.x * 64;
  const int valid = (nb + 64 <= N_NODES) ? 64 : (N_NODES - nb);

  const int mlo = wid * 16;
  for (int m = mlo; m < mlo + 16; ++m) {
    if (m >= valid) break;
    zbuf[m][ln] = hin[(size_t)(nb + m) * 64 + ln];
  }
  __syncthreads();

  const int jb = wid * 16;
  float acc[16];
#pragma unroll
  for (int f = 0; f < 16; ++f) acc[f] = b[jb + f];
#pragma unroll
  for (int k = 0; k < 64; ++k) {
    float zk = zbuf[ln][k];
#pragma unroll
    for (int f = 0; f < 16; ++f)
      acc[f] = fmaf(zk, W[k * 64 + jb + f], acc[f]);
  }

  if (ln < valid) {
    const size_t base = (size_t)(nb + ln) * 64 + jb;
#pragma unroll
    for (int c = 0; c < 4; ++c) {
      float4 s = make_float4(tanhf(acc[c * 4 + 0]), tanhf(acc[c * 4 + 1]),
                             tanhf(acc[c * 4 + 2]), tanhf(acc[c * 4 + 3]));
      *(float4*)&hb[base + c * 4] = s;
    }
  }
}

// ---------------- per-graph mean pool (batch is sorted) ----------------
__global__ void pool_kernel(const float* __restrict__ hb, const int* __restrict__ goff,
                            float* __restrict__ out) {
  __shared__ float red[4][64];
  int g = blockIdx.x;
  int s = goff[g], e = goff[g + 1];
  int j = threadIdx.x & 63, w = threadIdx.x >> 6;
  float acc = 0.0f;
  for (int r = s + w; r < e; r += 4) acc += hb[(size_t)r * 64 + j];
  red[w][j] = acc;
  __syncthreads();
  if (w == 0) {
    float tt = red[0][j] + red[1][j] + red[2][j] + red[3][j];
    out[g * 64 + j] = tt / fmaxf((float)(e - s), 1.0f);
  }
}

// ---------------- launch ----------------
extern "C" void kernel_launch(void* const* d_in, const int* in_sizes, int n_in,
                              void* d_out, int out_size, void* d_ws, size_t ws_size,
                              hipStream_t stream) {
  const float* x     = (const float*)d_in[0];
  const int*   ei    = (const int*)d_in[1];
  const int*   batch = (const int*)d_in[2];
  const float* c1_W1 = (const float*)d_in[3];
  const float* c1_b1 = (const float*)d_in[4];
  const float* c1_W2 = (const float*)d_in[5];
  const float* c1_b2 = (const float*)d_in[6];
  const float* c1_g  = (const float*)d_in[7];
  const float* c1_be = (const float*)d_in[8];
  const float* c1_m  = (const float*)d_in[9];
  const float* c1_v  = (const float*)d_in[10];
  const float* cs_W1 = (const float*)d_in[11];
  const float* cs_b1 = (const float*)d_in[12];
  const float* cs_W2 = (const float*)d_in[13];
  const float* cs_b2 = (const float*)d_in[14];
  const float* cs_g  = (const float*)d_in[15];
  const float* cs_be = (const float*)d_in[16];
  const float* cs_m  = (const float*)d_in[17];
  const float* cs_v  = (const float*)d_in[18];
  const float* lin_W = (const float*)d_in[19];
  const float* lin_b = (const float*)d_in[20];
  float* out = (float*)d_out;

  size_t cur = 0;
  auto take = [&](size_t bytes) -> void* {
    void* p = (char*)d_ws + cur;
    cur += (bytes + 255) & ~(size_t)255;
    return p;
  };
  int* cnt  = (int*)take(N_NODES * sizeof(int));
  size_t zbytes = cur;                       // only cnt needs zeroing
  int* goff = (int*)take((N_GRAPHS + 1) * sizeof(int));
  int* csr  = (int*)take((size_t)N_NODES * CAP * sizeof(int));
  float* bufA = (float*)take((size_t)N_NODES * HDIM * sizeof(float));
  float* bufB = (float*)take((size_t)N_NODES * HDIM * sizeof(float));
  (void)ws_size; (void)in_sizes; (void)n_in; (void)out_size;

  hipMemsetAsync(d_ws, 0, zbytes, stream);

  fill_kernel<<<RNG * CHUNKS, 256, 0, stream>>>(ei, cnt, csr);
  goff_kernel<<<1, 256, 0, stream>>>(batch, goff);

  const int NBLK = (N_NODES + 63) / 64;      // 1563

  // conv1: x -> bufA
  conv_kernel<false><<<NBLK, 256, 0, stream>>>(x, bufA, cnt, csr,
      c1_W1, c1_b1, c1_W2, c1_b2, c1_g, c1_be, c1_m, c1_v);

  // 4 residual convs, ping-pong A<->B
  float* srcp = bufA;
  float* dstp = bufB;
  for (int l = 0; l < N_RES; ++l) {
    conv_kernel<true><<<NBLK, 256, 0, stream>>>(srcp, dstp, cnt, csr,
        cs_W1 + l * 4096, cs_b1 + l * 64, cs_W2 + l * 4096, cs_b2 + l * 64,
        cs_g + l * 64, cs_be + l * 64, cs_m + l * 64, cs_v + l * 64);
    float* tmp = srcp; srcp = dstp; dstp = tmp;
  }
  // final h is in srcp (== bufA); head writes dstp (== bufB)
  head_kernel<<<NBLK, 256, 0, stream>>>(srcp, dstp, lin_W, lin_b);
  pool_kernel<<<N_GRAPHS, 256, 0, stream>>>(dstp, goff, out);
}